// Round 21
// baseline (128.893 us; speedup 1.0000x reference)
//
#include <hip/hip_runtime.h>

#define KK  128   // samples per ray
#define RPW 4     // rays per wave (wave-private); 16 lanes per ray in build
#define TPB 128   // 2 independent waves per block; 8.3 KB LDS/block

__global__ __launch_bounds__(TPB, 8)
void nerf_sample_kernel(const float* __restrict__ Wg,
                        const float* __restrict__ Zg,
                        const float* __restrict__ Ug,
                        const float* __restrict__ Tg,
                        float* __restrict__ Og)
{
    // per-wave: 4x128 cdf (swizzled) + 4x132 borders = 1040 floats (4160 B)
    __shared__ float S[2 * 1040];
    const int lane = threadIdx.x & 63;
    const int wvid = threadIdx.x >> 6;
    float* CW = S + wvid * 1040;        // cdf rows
    float* BW = CW + 512;               // border rows (stride 132)

    const int r   = lane >> 4;          // build: ray slot 0..3
    const int h   = lane & 15;          // build: owns elements [8h, 8h+8)
    const int swz = r << 3;             // 8-float-block XOR swizzle (cdf rows)
    float* Srow = CW + r * KK;
    float* Brow = BW + r * 132;

    const size_t grp   = (size_t)blockIdx.x * 2 + wvid;
    const size_t gbase = grp * (RPW * KK);
    const size_t rbase = gbase + (size_t)r * KK;

    // ---- phase-C it=0 prefetch: wave-linear 1KB loads ----
    float4 cu = *(const float4*)(Ug + gbase + 4 * lane);
    float4 ct = *(const float4*)(Tg + gbase + 4 * lane);

    // ---- load own 8 weights; w' = fl32(w + 1e-5f) ----
    float x[8];
    {
        const float* wp = Wg + rbase + 8 * h;
        #pragma unroll
        for (int e = 0; e < 2; ++e) {
            float4 v = *(const float4*)(wp + 4 * e);
            x[4*e+0] = v.x + 1e-5f;
            x[4*e+1] = v.y + 1e-5f;
            x[4*e+2] = v.z + 1e-5f;
            x[4*e+3] = v.w + 1e-5f;
        }
    }

    // ---- load own 8 z values (in flight during tot/scan) ----
    float zr[8];
    {
        const float* zp = Zg + rbase + 8 * h;
        float4 v0 = *(const float4*)(zp);
        float4 v1 = *(const float4*)(zp + 4);
        zr[0]=v0.x; zr[1]=v0.y; zr[2]=v0.z; zr[3]=v0.w;
        zr[4]=v1.x; zr[5]=v1.y; zr[6]=v1.z; zr[7]=v1.w;
    }

    // ---- tot: npyv model, EXACT R8 grouping (R20 verbatim) ----
    float tot;
    {
        float Cc[8];
        #pragma unroll
        for (int j = 0; j < 8; ++j) {
            float a = x[j] + __shfl_xor(x[j], 8);
            float b = a    + __shfl_xor(a, 2);
            float c = b    + __shfl_xor(b, 4);
            Cc[j]   = c    + __shfl_xor(c, 1);
        }
        float V0 = Cc[0] + Cc[4];
        float V1 = Cc[1] + Cc[5];
        float V2 = Cc[2] + Cc[6];
        float V3 = Cc[3] + Cc[7];
        tot = (V0 + V2) + (V1 + V3);
    }

    // ---- pdf: IEEE f32 divide ----
    #pragma unroll
    for (int j = 0; j < 8; ++j) x[j] = x[j] / tot;

    // ---- BK scan: levels 1-3 lane-local (R20 verbatim) ----
    x[1] = x[1] + x[0];  x[3] = x[3] + x[2];
    x[5] = x[5] + x[4];  x[7] = x[7] + x[6];
    x[3] = x[3] + x[1];  x[7] = x[7] + x[5];
    x[7] = x[7] + x[3];

    // ---- segment-space BK over 16 lanes (R20 verbatim) ----
    {
        float s     = x[7];
        float sx1   = __shfl_xor(s, 1);
        float pair  = s + sx1;
        float pairx2 = __shfl_xor(pair, 2);
        float quad  = pair + pairx2;
        float quadx4 = __shfl_xor(quad, 4);
        float oct   = quad + quadx4;
        float octx8 = __shfl_xor(oct, 8);

        float tP = (h & 8) ? octx8 : 0.0f;
        tP = (h & 4) ? (quadx4 + tP) : tP;
        tP = (h & 2) ? (pairx2 + tP) : tP;
        float P = (h & 1) ? (sx1 + tP) : tP;

        float c5v  = pairx2 + quadx4;
        float c9v  = pairx2 + octx8;
        float c11v = quadx4 + octx8;
        float c13v = pairx2 + c11v;
        float C =
            (h ==  0) ? s :
            (h ==  1) ? pair :
            (h ==  2) ? s + pairx2 :
            (h ==  3) ? quad :
            (h ==  4) ? s + quadx4 :
            (h ==  5) ? pair + quadx4 :
            (h ==  6) ? s + c5v :
            (h ==  7) ? oct :
            (h ==  8) ? s + octx8 :
            (h ==  9) ? pair + octx8 :
            (h == 10) ? s + c9v :
            (h == 11) ? quad + octx8 :
            (h == 12) ? s + c11v :
            (h == 13) ? pair + c11v :
            (h == 14) ? s + c13v :
                        oct + octx8;
        x[7] = C;

        x[3] = x[3] + P;
        x[1] = x[1] + P;  x[5] = x[5] + x[3];
        x[0] = x[0] + P;  x[2] = x[2] + x[1];
        x[4] = x[4] + x[3];  x[6] = x[6] + x[5];
    }

    // ---- write cdf to wave-private LDS (8-float-block XOR swizzle) ----
    *(float4*)(Srow + ((8*h    ) ^ swz)) = make_float4(x[0], x[1], x[2], x[3]);
    *(float4*)(Srow + ((8*h + 4) ^ swz)) = make_float4(x[4], x[5], x[6], x[7]);

    // ---- borders (R20 verbatim) ----
    {
        float zprev = __shfl_up(zr[7], 1);
        float B0 = (h == 0) ? zr[0] : 0.5f * (zr[0] + zprev);
        float B1 = 0.5f * (zr[1] + zr[0]);
        float B2 = 0.5f * (zr[2] + zr[1]);
        float B3 = 0.5f * (zr[3] + zr[2]);
        float B4 = 0.5f * (zr[4] + zr[3]);
        float B5 = 0.5f * (zr[5] + zr[4]);
        float B6 = 0.5f * (zr[6] + zr[5]);
        float B7 = 0.5f * (zr[7] + zr[6]);
        *(float4*)(Brow + 8*h    ) = make_float4(B0, B1, B2, B3);
        *(float4*)(Brow + 8*h + 4) = make_float4(B4, B5, B6, B7);
        if (h == 15) Brow[128] = zr[7];
    }

    __builtin_amdgcn_sched_barrier(0);
    __builtin_amdgcn_wave_barrier();
    __builtin_amdgcn_sched_barrier(0);

    // ---- phase C: shared-skeleton search + b128 block resolve ----
    const float EPSL = 1.0f - 1.8e-7f;
    const float EPSH = 1.0f + 1.8e-7f;
    const int rhalf = lane >> 5;

    #pragma unroll
    for (int it = 0; it < 2; ++it) {
        float4 uu4 = cu, tt4 = ct;
        if (it == 0) {
            cu = *(const float4*)(Ug + gbase + 256 + 4 * lane);
            ct = *(const float4*)(Tg + gbase + 256 + 4 * lane);
        }

        const int rr = 2 * it + rhalf;
        const float* crow = CW + rr * KK;
        const float* brow = BW + rr * 132;
        const int csw = rr << 3;

        // skeleton: positions tested at s=64,32,16 (wave-broadcast reads)
        const float w63  = crow[ 63 ^ csw];
        const float w31  = crow[ 31 ^ csw];
        const float w95  = crow[ 95 ^ csw];
        const float w15  = crow[ 15 ^ csw];
        const float w47  = crow[ 47 ^ csw];
        const float w79  = crow[ 79 ^ csw];
        const float w111 = crow[111 ^ csw];

        float uu[4] = {uu4.x, uu4.y, uu4.z, uu4.w};
        float tv[4] = {tt4.x, tt4.y, tt4.z, tt4.w};
        float res[4];
        #pragma unroll
        for (int i = 0; i < 4; ++i) {
            const float ul = uu[i] * EPSL;
            const float uh = uu[i] * EPSH;
            float last = 0.0f;              // value at the last passed test
            int hh = 0;

            // s=64 (shared)
            if (w63 <= uh) { hh = 64; last = w63; }
            // s=32 (shared pair)
            { float b = hh ? w95 : w31;
              if (b <= uh) { hh += 32; last = b; } }
            // s=16 (shared quad, select by hh>>5)
            { const int st = hh >> 5;
              float b = (st == 0) ? w15 : (st == 1) ? w47 : (st == 2) ? w79 : w111;
              if (b <= uh) { hh += 16; last = b; } }
            // s=8, s=4 (per-chain)
            { float b = crow[(hh + 7) ^ csw];
              if (b <= uh) { hh += 8; last = b; } }
            { float b = crow[(hh + 3) ^ csw];
              if (b <= uh) { hh += 4; last = b; } }
            // s=2, s=1: one b128 covers logical [hh, hh+3] (hh 4-aligned;
            // csw multiple of 8 -> block stays contiguous after XOR)
            { float4 wb = *(const float4*)(crow + (hh ^ csw));
              int o = 0;
              if (wb.y <= uh) { o = 2; last = wb.y; }
              float b1 = o ? wb.z : wb.x;
              if (b1 <= uh) { o += 1; last = b1; } 
              hh += o; }

            const int hi = hh;                    // #{cdf<=uh}, <=127 structurally
            int li = hi;
            // hedge: crow[hi-1] == last (search invariant) -> LDS only if in window
            if (hi > 0 && last > ul) {
                --li;
                while (li > 0 && crow[(li - 1) ^ csw] > ul) --li;
            }

            float lb = brow[hi], rb = brow[hi + 1];
            float r1 = lb * (1.0f - tv[i]) + rb * tv[i];
            if (li != hi) {
                float lb2 = brow[li], rb2 = brow[li + 1];
                float r0 = lb2 * (1.0f - tv[i]) + rb2 * tv[i];
                r1 = 0.5f * (r0 + r1);
            }
            res[i] = r1;
        }
        *(float4*)(Og + gbase + it * 256 + 4 * lane) =
            make_float4(res[0], res[1], res[2], res[3]);
    }
}

extern "C" void kernel_launch(void* const* d_in, const int* in_sizes, int n_in,
                              void* d_out, int out_size, void* d_ws, size_t ws_size,
                              hipStream_t stream)
{
    // inputs: 0=rays (unused), 1=weights, 2=z_samp, 3=u, 4=interval_interp
    const float* Wg = (const float*)d_in[1];
    const float* Zg = (const float*)d_in[2];
    const float* Ug = (const float*)d_in[3];
    const float* Tg = (const float*)d_in[4];
    float* Og = (float*)d_out;

    const int nrays  = in_sizes[1] / KK;        // 262144
    const int blocks = nrays / (2 * RPW);       // 32768 (2 waves x 4 rays)

    nerf_sample_kernel<<<dim3(blocks), dim3(TPB), 0, stream>>>(Wg, Zg, Ug, Tg, Og);
}